// Round 4
// baseline (421.168 us; speedup 1.0000x reference)
//
#include <hip/hip_runtime.h>
#include <hip/hip_fp16.h>
#include <stdint.h>

#define NB  32
#define NLQ 128
#define NLK 4096
#define NDK 256
#define NDV 256
#define KT  32
#define SPLITS 16

typedef _Float16 f16;
typedef _Float16 f16x4 __attribute__((ext_vector_type(4)));
typedef _Float16 f16x8 __attribute__((ext_vector_type(8)));
typedef float    f32x4 __attribute__((ext_vector_type(4)));

// ---------------- Kernel 1: per (key-split s, batch b) flash partials -------
// 8 waves x 16 queries = 128 queries per block; K/V staged f32->f16 in LDS.
// Both K and V tiles: [32 keys][256 dims] f16, element-swizzled
//   elem = row*256 + (col ^ ((row&15)<<3))   (bank-balanced b128 / u16 reads)
__global__ __launch_bounds__(512, 4) void fvta_part1(
    const float* __restrict__ q_, const float* __restrict__ k_,
    const float* __restrict__ v_, const int* __restrict__ mask_,
    f16* __restrict__ accw, float* __restrict__ mlw)
{
    __shared__ __align__(16) f16 KA[2][KT * NDK];
    __shared__ __align__(16) f16 VA[2][KT * NDV];

    const int tid = threadIdx.x, w = tid >> 6, lane = tid & 63;
    const int l15 = lane & 15, lhi = lane >> 4;
    const int s = blockIdx.x, b = blockIdx.y, S = gridDim.x;
    const int slice = NLK / S, nt = slice / KT, kbase = s * slice;
    const float NEG = -__builtin_inff();

    const float* kb = k_ + ((size_t)b * NLK + kbase) * NDK;
    const float* vb = v_ + ((size_t)b * NLK + kbase) * NDV;
    const int*   mb = mask_ + b * NLK + kbase;

    // ---- Q fragments: lane holds Q[w*16+l15][kd*32 + lhi*8 + 0..8)
    f16x8 qf[8];
    {
        const float* qrow = q_ + ((size_t)b * NLQ + w * 16 + l15) * NDK + lhi * 8;
        #pragma unroll
        for (int kd = 0; kd < 8; ++kd) {
            f32x4 x = *(const f32x4*)(qrow + kd * 32);
            f32x4 y = *(const f32x4*)(qrow + kd * 32 + 4);
            f16x8 f;
            f[0]=(f16)x[0]; f[1]=(f16)x[1]; f[2]=(f16)x[2]; f[3]=(f16)x[3];
            f[4]=(f16)y[0]; f[5]=(f16)y[1]; f[6]=(f16)y[2]; f[7]=(f16)y[3];
            qf[kd] = f;
        }
    }

    f32x4 accu[16];
    #pragma unroll
    for (int i = 0; i < 16; ++i) accu[i] = (f32x4){0.f, 0.f, 0.f, 0.f};
    float m_run = NEG, l_run = 0.f;

    f32x4 ks[4], vs[4];   // staged f32 for next tile (issue early, write late)

    // thread's staging coords: kk = r*8 + w (const per reg), d = lane*4
    auto stage = [&](f16* KAb, f16* VAb) {
        #pragma unroll
        for (int r = 0; r < 4; ++r) {
            const int kk = r * 8 + w;
            const int d  = lane * 4;
            const int e  = kk * NDK + (d ^ ((kk & 15) << 3));
            f32x4 x = ks[r];
            f16x4 hh; hh[0]=(f16)x[0]; hh[1]=(f16)x[1]; hh[2]=(f16)x[2]; hh[3]=(f16)x[3];
            *(f16x4*)(KAb + e) = hh;
            f32x4 y = vs[r];
            f16x4 gg; gg[0]=(f16)y[0]; gg[1]=(f16)y[1]; gg[2]=(f16)y[2]; gg[3]=(f16)y[3];
            *(f16x4*)(VAb + e) = gg;
        }
    };

    // prologue: load + stage tile 0
    #pragma unroll
    for (int r = 0; r < 4; ++r) {
        const int off = (r * 512 + tid) * 4;
        ks[r] = *(const f32x4*)(kb + off);
        vs[r] = *(const f32x4*)(vb + off);
    }
    stage(KA[0], VA[0]);
    __syncthreads();

    const int swz = l15 << 3;   // K read swizzle: row&15 == l15 for both halves

    for (int t = 0; t < nt; ++t) {
        const int cur = t & 1;
        if (t + 1 < nt) {   // prefetch next tile (stays in flight through compute)
            const float* ksrc = kb + (size_t)(t + 1) * KT * NDK;
            const float* vsrc = vb + (size_t)(t + 1) * KT * NDV;
            #pragma unroll
            for (int r = 0; r < 4; ++r) {
                const int off = (r * 512 + tid) * 4;
                ks[r] = *(const f32x4*)(ksrc + off);
                vs[r] = *(const f32x4*)(vsrc + off);
            }
        }
        const int k0 = t * KT;

        // ---- QK^T, both 16-key halves (A = K rows, B = Q)
        f32x4 s4a = (f32x4){0.f,0.f,0.f,0.f}, s4b = s4a;
        {
            const f16* k0p = &KA[cur][(0 * 16 + l15) * NDK];
            const f16* k1p = &KA[cur][(1 * 16 + l15) * NDK];
            #pragma unroll
            for (int kd = 0; kd < 8; ++kd) {
                const int col = (kd * 32 + lhi * 8) ^ swz;
                f16x8 kfa = *(const f16x8*)(k0p + col);
                s4a = __builtin_amdgcn_mfma_f32_16x16x32_f16(kfa, qf[kd], s4a, 0, 0, 0);
                f16x8 kfb = *(const f16x8*)(k1p + col);
                s4b = __builtin_amdgcn_mfma_f32_16x16x32_f16(kfb, qf[kd], s4b, 0, 0, 0);
            }
        }
        // s4a[j] = S[key=k0+lhi*4+j][q=l15], s4b[j] = S[key=k0+16+lhi*4+j][q=l15]

        // ---- mask -> -inf, online softmax over 32 keys
        const int4 m4a = *(const int4*)(mb + k0 + lhi * 4);
        const int4 m4b = *(const int4*)(mb + k0 + 16 + lhi * 4);
        float sa[4], sb[4];
        sa[0] = m4a.x ? NEG : s4a[0]; sa[1] = m4a.y ? NEG : s4a[1];
        sa[2] = m4a.z ? NEG : s4a[2]; sa[3] = m4a.w ? NEG : s4a[3];
        sb[0] = m4b.x ? NEG : s4b[0]; sb[1] = m4b.y ? NEG : s4b[1];
        sb[2] = m4b.z ? NEG : s4b[2]; sb[3] = m4b.w ? NEG : s4b[3];

        float tmax = fmaxf(fmaxf(fmaxf(sa[0], sa[1]), fmaxf(sa[2], sa[3])),
                           fmaxf(fmaxf(sb[0], sb[1]), fmaxf(sb[2], sb[3])));
        tmax = fmaxf(tmax, __shfl_xor(tmax, 16, 64));
        tmax = fmaxf(tmax, __shfl_xor(tmax, 32, 64));
        const float mnew = fmaxf(m_run, tmax);
        const bool  dead = (mnew == NEG);
        const float scale = dead ? 1.f : __expf(m_run - mnew);
        float pa4[4], pb4[4];
        #pragma unroll
        for (int j = 0; j < 4; ++j) {
            pa4[j] = dead ? 0.f : __expf(sa[j] - mnew);
            pb4[j] = dead ? 0.f : __expf(sb[j] - mnew);
        }
        float ps = (pa4[0] + pa4[1]) + (pa4[2] + pa4[3])
                 + (pb4[0] + pb4[1]) + (pb4[2] + pb4[3]);
        ps += __shfl_xor(ps, 16, 64);
        ps += __shfl_xor(ps, 32, 64);
        l_run = l_run * scale + ps;
        m_run = mnew;

        f16x4 pa, pb;
        pa[0]=(f16)pa4[0]; pa[1]=(f16)pa4[1]; pa[2]=(f16)pa4[2]; pa[3]=(f16)pa4[3];
        pb[0]=(f16)pb4[0]; pb[1]=(f16)pb4[1]; pb[2]=(f16)pb4[2]; pb[3]=(f16)pb4[3];

        if (!__all(scale == 1.f)) {
            float scj[4];
            #pragma unroll
            for (int j = 0; j < 4; ++j) scj[j] = __shfl(scale, lhi * 4 + j, 64);
            #pragma unroll
            for (int d = 0; d < 16; ++d) {
                accu[d][0] *= scj[0]; accu[d][1] *= scj[1];
                accu[d][2] *= scj[2]; accu[d][3] *= scj[3];
            }
        }

        // ---- PV: B frag = V[row=h*16+lhi*4+j][dv=d*16+l15] via swizzled u16 reads
        {
            const f16* VL = &VA[cur][0];
            #pragma unroll
            for (int h = 0; h < 2; ++h) {
                const f16x4 pfrag = h ? pb : pa;
                #pragma unroll
                for (int d = 0; d < 16; ++d) {
                    f16x4 vf;
                    #pragma unroll
                    for (int j = 0; j < 4; ++j) {
                        const int row = h * 16 + lhi * 4 + j;
                        const int col = (d * 16 + l15) ^ ((row & 15) << 3);
                        vf[j] = VL[row * NDV + col];
                    }
                    accu[d] = __builtin_amdgcn_mfma_f32_16x16x16f16(
                        pfrag, vf, accu[d], 0, 0, 0);
                }
            }
        }

        if (t + 1 < nt) stage(KA[cur ^ 1], VA[cur ^ 1]);
        __syncthreads();
    }

    // ---- write partials {acc (f16), m, l (f32)} to workspace
    const size_t base = (size_t)(b * S + s) * NLQ + w * 16;
    #pragma unroll
    for (int j = 0; j < 4; ++j) {
        f16* dst = accw + (base + lhi * 4 + j) * NDV + l15;
        #pragma unroll
        for (int d = 0; d < 16; ++d) dst[d * 16] = (f16)accu[d][j];
    }
    if (lane < 16) {
        mlw[(base + lane) * 2]     = m_run;
        mlw[(base + lane) * 2 + 1] = l_run;
    }
}

// ---------------- Kernel 2: merge key-splits, q-length mask, mean ----------
__global__ __launch_bounds__(256) void fvta_merge(
    const f16* __restrict__ accw, const float* __restrict__ mlw,
    const int* __restrict__ qlen_, float* __restrict__ out_, int S)
{
    __shared__ float fac[16][SPLITS + 1];
    const int qc = blockIdx.x, b = blockIdx.y, tid = threadIdx.x;
    const int len = qlen_[b];
    const float NEG = -__builtin_inff();

    if (tid < 16) {
        const int q = qc * 16 + tid;
        if (q < len) {
            float gm = NEG;
            for (int ss = 0; ss < S; ++ss)
                gm = fmaxf(gm, mlw[((size_t)(b * S + ss) * NLQ + q) * 2]);
            float L = 0.f;
            for (int ss = 0; ss < S; ++ss) {
                const float m = mlw[((size_t)(b * S + ss) * NLQ + q) * 2];
                const float l = mlw[((size_t)(b * S + ss) * NLQ + q) * 2 + 1];
                if (m != NEG) L += l * __expf(m - gm);
            }
            for (int ss = 0; ss < S; ++ss) {
                const float m = mlw[((size_t)(b * S + ss) * NLQ + q) * 2];
                fac[tid][ss] = (gm != NEG && L > 0.f && m != NEG)
                             ? __expf(m - gm) / L : 0.f;
            }
        } else {
            for (int ss = 0; ss < S; ++ss) fac[tid][ss] = 0.f;
        }
    }
    __syncthreads();

    float sum = 0.f;
    for (int qq = 0; qq < 16; ++qq) {
        const int q = qc * 16 + qq;
        for (int ss = 0; ss < S; ++ss) {
            const float f = fac[qq][ss];
            if (f != 0.f)
                sum += (float)accw[((size_t)(b * S + ss) * NLQ + q) * NDV + tid] * f;
        }
    }
    atomicAdd(&out_[b * NDV + tid], sum * (1.f / NLQ));
}

extern "C" void kernel_launch(void* const* d_in, const int* in_sizes, int n_in,
                              void* d_out, int out_size, void* d_ws, size_t ws_size,
                              hipStream_t stream) {
    const float* q    = (const float*)d_in[0];
    const int*   qlen = (const int*)d_in[1];
    const float* k    = (const float*)d_in[2];
    const float* v    = (const float*)d_in[3];
    const int*   mask = (const int*)d_in[4];
    float* out = (float*)d_out;

    int S = SPLITS;   // key splits; shrink if workspace is small (correct at any S)
    while (S > 1 && ((size_t)NB * S * NLQ * NDV * 2 + (size_t)NB * S * NLQ * 8) > ws_size)
        S >>= 1;
    f16*   accw = (f16*)d_ws;
    float* mlw  = (float*)((char*)d_ws + (size_t)NB * S * NLQ * NDV * 2);

    hipMemsetAsync(out, 0, (size_t)out_size * sizeof(float), stream);
    dim3 g1(S, NB);
    fvta_part1<<<g1, 512, 0, stream>>>(q, k, v, mask, accw, mlw);
    dim3 g2(NLQ / 16, NB);
    fvta_merge<<<g2, 256, 0, stream>>>(accw, mlw, qlen, out, S);
}

// Round 5
// 221.756 us; speedup vs baseline: 1.8992x; 1.8992x over previous
//
#include <hip/hip_runtime.h>
#include <hip/hip_fp16.h>
#include <stdint.h>

#define NB  32
#define NLQ 128
#define NLK 4096
#define NDK 256
#define NDV 256
#define KT  32
#define SPLITS 16

typedef _Float16 f16;
typedef _Float16 f16x4 __attribute__((ext_vector_type(4)));
typedef _Float16 f16x8 __attribute__((ext_vector_type(8)));
typedef float    f32x4 __attribute__((ext_vector_type(4)));

// ---------------- Kernel 1: per (key-split s, batch b) flash partials -------
// 8 waves x 16 queries = 128 queries per block; K/V staged f32->f16 in LDS.
// Both K and V tiles: [32 keys][256 dims] f16, element-swizzled
//   elem = row*256 + (col ^ ((row&15)<<3))   (bank-balanced b128 / u16 reads)
// NOTE: no min-waves in launch_bounds — forcing 4 waves/EU capped VGPR at 64
// and spilled ~1 GB to scratch (round-4 regression). 128 VGPR + 64KB LDS
// already fits 2 blocks/CU, which is all S=16's 512 blocks need.
__global__ __launch_bounds__(512) void fvta_part1(
    const float* __restrict__ q_, const float* __restrict__ k_,
    const float* __restrict__ v_, const int* __restrict__ mask_,
    f16* __restrict__ accw, float* __restrict__ mlw)
{
    __shared__ __align__(16) f16 KA[2][KT * NDK];
    __shared__ __align__(16) f16 VA[2][KT * NDV];

    const int tid = threadIdx.x, w = tid >> 6, lane = tid & 63;
    const int l15 = lane & 15, lhi = lane >> 4;
    const int s = blockIdx.x, b = blockIdx.y, S = gridDim.x;
    const int slice = NLK / S, nt = slice / KT, kbase = s * slice;
    const float NEG = -__builtin_inff();

    const float* kb = k_ + ((size_t)b * NLK + kbase) * NDK;
    const float* vb = v_ + ((size_t)b * NLK + kbase) * NDV;
    const int*   mb = mask_ + b * NLK + kbase;

    // ---- Q fragments: lane holds Q[w*16+l15][kd*32 + lhi*8 + 0..8)
    f16x8 qf[8];
    {
        const float* qrow = q_ + ((size_t)b * NLQ + w * 16 + l15) * NDK + lhi * 8;
        #pragma unroll
        for (int kd = 0; kd < 8; ++kd) {
            f32x4 x = *(const f32x4*)(qrow + kd * 32);
            f32x4 y = *(const f32x4*)(qrow + kd * 32 + 4);
            f16x8 f;
            f[0]=(f16)x[0]; f[1]=(f16)x[1]; f[2]=(f16)x[2]; f[3]=(f16)x[3];
            f[4]=(f16)y[0]; f[5]=(f16)y[1]; f[6]=(f16)y[2]; f[7]=(f16)y[3];
            qf[kd] = f;
        }
    }

    f32x4 accu[16];
    #pragma unroll
    for (int i = 0; i < 16; ++i) accu[i] = (f32x4){0.f, 0.f, 0.f, 0.f};
    float m_run = NEG, l_run = 0.f;

    f32x4 ks[4], vs[4];   // staged f32 for next tile (issue early, write late)

    // thread's staging coords: kk = r*8 + w (const per reg), d = lane*4
    auto stage = [&](f16* KAb, f16* VAb) {
        #pragma unroll
        for (int r = 0; r < 4; ++r) {
            const int kk = r * 8 + w;
            const int d  = lane * 4;
            const int e  = kk * NDK + (d ^ ((kk & 15) << 3));
            f32x4 x = ks[r];
            f16x4 hh; hh[0]=(f16)x[0]; hh[1]=(f16)x[1]; hh[2]=(f16)x[2]; hh[3]=(f16)x[3];
            *(f16x4*)(KAb + e) = hh;
            f32x4 y = vs[r];
            f16x4 gg; gg[0]=(f16)y[0]; gg[1]=(f16)y[1]; gg[2]=(f16)y[2]; gg[3]=(f16)y[3];
            *(f16x4*)(VAb + e) = gg;
        }
    };

    // prologue: load + stage tile 0
    #pragma unroll
    for (int r = 0; r < 4; ++r) {
        const int off = (r * 512 + tid) * 4;
        ks[r] = *(const f32x4*)(kb + off);
        vs[r] = *(const f32x4*)(vb + off);
    }
    stage(KA[0], VA[0]);
    __syncthreads();

    const int swz = l15 << 3;   // K read swizzle: row&15 == l15 for both halves

    for (int t = 0; t < nt; ++t) {
        const int cur = t & 1;
        if (t + 1 < nt) {   // prefetch next tile (stays in flight through compute)
            const float* ksrc = kb + (size_t)(t + 1) * KT * NDK;
            const float* vsrc = vb + (size_t)(t + 1) * KT * NDV;
            #pragma unroll
            for (int r = 0; r < 4; ++r) {
                const int off = (r * 512 + tid) * 4;
                ks[r] = *(const f32x4*)(ksrc + off);
                vs[r] = *(const f32x4*)(vsrc + off);
            }
        }
        const int k0 = t * KT;

        // ---- QK^T, both 16-key halves (A = K rows, B = Q)
        f32x4 s4a = (f32x4){0.f,0.f,0.f,0.f}, s4b = s4a;
        {
            const f16* k0p = &KA[cur][(0 * 16 + l15) * NDK];
            const f16* k1p = &KA[cur][(1 * 16 + l15) * NDK];
            #pragma unroll
            for (int kd = 0; kd < 8; ++kd) {
                const int col = (kd * 32 + lhi * 8) ^ swz;
                f16x8 kfa = *(const f16x8*)(k0p + col);
                s4a = __builtin_amdgcn_mfma_f32_16x16x32_f16(kfa, qf[kd], s4a, 0, 0, 0);
                f16x8 kfb = *(const f16x8*)(k1p + col);
                s4b = __builtin_amdgcn_mfma_f32_16x16x32_f16(kfb, qf[kd], s4b, 0, 0, 0);
            }
        }
        // s4a[j] = S[key=k0+lhi*4+j][q=l15], s4b[j] = S[key=k0+16+lhi*4+j][q=l15]

        // ---- mask -> -inf, online softmax over 32 keys
        const int4 m4a = *(const int4*)(mb + k0 + lhi * 4);
        const int4 m4b = *(const int4*)(mb + k0 + 16 + lhi * 4);
        float sa[4], sb[4];
        sa[0] = m4a.x ? NEG : s4a[0]; sa[1] = m4a.y ? NEG : s4a[1];
        sa[2] = m4a.z ? NEG : s4a[2]; sa[3] = m4a.w ? NEG : s4a[3];
        sb[0] = m4b.x ? NEG : s4b[0]; sb[1] = m4b.y ? NEG : s4b[1];
        sb[2] = m4b.z ? NEG : s4b[2]; sb[3] = m4b.w ? NEG : s4b[3];

        float tmax = fmaxf(fmaxf(fmaxf(sa[0], sa[1]), fmaxf(sa[2], sa[3])),
                           fmaxf(fmaxf(sb[0], sb[1]), fmaxf(sb[2], sb[3])));
        tmax = fmaxf(tmax, __shfl_xor(tmax, 16, 64));
        tmax = fmaxf(tmax, __shfl_xor(tmax, 32, 64));
        const float mnew = fmaxf(m_run, tmax);
        const bool  dead = (mnew == NEG);
        const float scale = dead ? 1.f : __expf(m_run - mnew);
        float pa4[4], pb4[4];
        #pragma unroll
        for (int j = 0; j < 4; ++j) {
            pa4[j] = dead ? 0.f : __expf(sa[j] - mnew);
            pb4[j] = dead ? 0.f : __expf(sb[j] - mnew);
        }
        float ps = (pa4[0] + pa4[1]) + (pa4[2] + pa4[3])
                 + (pb4[0] + pb4[1]) + (pb4[2] + pb4[3]);
        ps += __shfl_xor(ps, 16, 64);
        ps += __shfl_xor(ps, 32, 64);
        l_run = l_run * scale + ps;
        m_run = mnew;

        f16x4 pa, pb;
        pa[0]=(f16)pa4[0]; pa[1]=(f16)pa4[1]; pa[2]=(f16)pa4[2]; pa[3]=(f16)pa4[3];
        pb[0]=(f16)pb4[0]; pb[1]=(f16)pb4[1]; pb[2]=(f16)pb4[2]; pb[3]=(f16)pb4[3];

        if (!__all(scale == 1.f)) {
            float scj[4];
            #pragma unroll
            for (int j = 0; j < 4; ++j) scj[j] = __shfl(scale, lhi * 4 + j, 64);
            #pragma unroll
            for (int d = 0; d < 16; ++d) {
                accu[d][0] *= scj[0]; accu[d][1] *= scj[1];
                accu[d][2] *= scj[2]; accu[d][3] *= scj[3];
            }
        }

        // ---- PV: B frag = V[row=h*16+lhi*4+j][dv=d*16+l15] via swizzled u16 reads
        {
            const f16* VL = &VA[cur][0];
            #pragma unroll
            for (int h = 0; h < 2; ++h) {
                const f16x4 pfrag = h ? pb : pa;
                #pragma unroll
                for (int d = 0; d < 16; ++d) {
                    f16x4 vf;
                    #pragma unroll
                    for (int j = 0; j < 4; ++j) {
                        const int row = h * 16 + lhi * 4 + j;
                        const int col = (d * 16 + l15) ^ ((row & 15) << 3);
                        vf[j] = VL[row * NDV + col];
                    }
                    accu[d] = __builtin_amdgcn_mfma_f32_16x16x16f16(
                        pfrag, vf, accu[d], 0, 0, 0);
                }
            }
        }

        if (t + 1 < nt) stage(KA[cur ^ 1], VA[cur ^ 1]);
        __syncthreads();
    }

    // ---- write partials {acc (f16), m, l (f32)} to workspace
    const size_t base = (size_t)(b * S + s) * NLQ + w * 16;
    #pragma unroll
    for (int j = 0; j < 4; ++j) {
        f16* dst = accw + (base + lhi * 4 + j) * NDV + l15;
        #pragma unroll
        for (int d = 0; d < 16; ++d) dst[d * 16] = (f16)accu[d][j];
    }
    if (lane < 16) {
        mlw[(base + lane) * 2]     = m_run;
        mlw[(base + lane) * 2 + 1] = l_run;
    }
}

// ---------------- Kernel 2: merge key-splits, q-length mask, mean ----------
__global__ __launch_bounds__(256) void fvta_merge(
    const f16* __restrict__ accw, const float* __restrict__ mlw,
    const int* __restrict__ qlen_, float* __restrict__ out_, int S)
{
    __shared__ float fac[16][SPLITS + 1];
    const int qc = blockIdx.x, b = blockIdx.y, tid = threadIdx.x;
    const int len = qlen_[b];
    const float NEG = -__builtin_inff();

    if (tid < 16) {
        const int q = qc * 16 + tid;
        if (q < len) {
            float gm = NEG;
            for (int ss = 0; ss < S; ++ss)
                gm = fmaxf(gm, mlw[((size_t)(b * S + ss) * NLQ + q) * 2]);
            float L = 0.f;
            for (int ss = 0; ss < S; ++ss) {
                const float m = mlw[((size_t)(b * S + ss) * NLQ + q) * 2];
                const float l = mlw[((size_t)(b * S + ss) * NLQ + q) * 2 + 1];
                if (m != NEG) L += l * __expf(m - gm);
            }
            for (int ss = 0; ss < S; ++ss) {
                const float m = mlw[((size_t)(b * S + ss) * NLQ + q) * 2];
                fac[tid][ss] = (gm != NEG && L > 0.f && m != NEG)
                             ? __expf(m - gm) / L : 0.f;
            }
        } else {
            for (int ss = 0; ss < S; ++ss) fac[tid][ss] = 0.f;
        }
    }
    __syncthreads();

    float sum = 0.f;
    for (int qq = 0; qq < 16; ++qq) {
        const int q = qc * 16 + qq;
        for (int ss = 0; ss < S; ++ss) {
            const float f = fac[qq][ss];
            if (f != 0.f)
                sum += (float)accw[((size_t)(b * S + ss) * NLQ + q) * NDV + tid] * f;
        }
    }
    atomicAdd(&out_[b * NDV + tid], sum * (1.f / NLQ));
}

extern "C" void kernel_launch(void* const* d_in, const int* in_sizes, int n_in,
                              void* d_out, int out_size, void* d_ws, size_t ws_size,
                              hipStream_t stream) {
    const float* q    = (const float*)d_in[0];
    const int*   qlen = (const int*)d_in[1];
    const float* k    = (const float*)d_in[2];
    const float* v    = (const float*)d_in[3];
    const int*   mask = (const int*)d_in[4];
    float* out = (float*)d_out;

    int S = SPLITS;   // key splits; shrink if workspace is small (correct at any S)
    while (S > 1 && ((size_t)NB * S * NLQ * NDV * 2 + (size_t)NB * S * NLQ * 8) > ws_size)
        S >>= 1;
    f16*   accw = (f16*)d_ws;
    float* mlw  = (float*)((char*)d_ws + (size_t)NB * S * NLQ * NDV * 2);

    hipMemsetAsync(out, 0, (size_t)out_size * sizeof(float), stream);
    dim3 g1(S, NB);
    fvta_part1<<<g1, 512, 0, stream>>>(q, k, v, mask, accw, mlw);
    dim3 g2(NLQ / 16, NB);
    fvta_merge<<<g2, 256, 0, stream>>>(accw, mlw, qlen, out, S);
}

// Round 6
// 139.791 us; speedup vs baseline: 3.0128x; 1.5863x over previous
//
#include <hip/hip_runtime.h>
#include <hip/hip_fp16.h>
#include <stdint.h>

#define NB  32
#define NLQ 128
#define NLK 4096
#define NDK 256
#define NDV 256
#define KT  32
#define SPLITS 8

typedef _Float16 f16;
typedef _Float16 f16x4 __attribute__((ext_vector_type(4)));
typedef _Float16 f16x8 __attribute__((ext_vector_type(8)));
typedef float    f32x4 __attribute__((ext_vector_type(4)));

// ---------------- Kernel 1: per (key-split s, batch b) flash partials -------
// 8 waves x 16 queries = 128 queries per block.
// K: reg-staged f32->f16 into swizzled dbuf LDS (verified r3/r5, 0 conflicts).
// V: PV B-fragments read f32 DIRECT from global (verified r0) — keeps many
//    independent loads outstanding through compute instead of burst+drain.
// Masks: whole 512-key slice preloaded to LDS once (off critical path).
// VGPR budget deliberately <=128: at 128 a second 8-wave block does NOT
// co-reside (r4 vs r5 A/B), so we feed the pipe from within one block.
__global__ __launch_bounds__(512) void fvta_part1(
    const float* __restrict__ q_, const float* __restrict__ k_,
    const float* __restrict__ v_, const int* __restrict__ mask_,
    f16* __restrict__ accw, float* __restrict__ mlw)
{
    __shared__ __align__(16) f16 KA[2][KT * NDK];
    __shared__ __align__(16) int MK[NLK / SPLITS];

    const int tid = threadIdx.x, w = tid >> 6, lane = tid & 63;
    const int l15 = lane & 15, lhi = lane >> 4;
    const int s = blockIdx.x, b = blockIdx.y, S = gridDim.x;
    const int slice = NLK / S, nt = slice / KT, kbase = s * slice;
    const float NEG = -__builtin_inff();

    const float* kb = k_ + ((size_t)b * NLK + kbase) * NDK;
    const float* vb = v_ + ((size_t)b * NLK + kbase) * NDV;
    const int*   mb = mask_ + b * NLK + kbase;

    // ---- masks for the whole slice -> LDS (one coalesced load per thread)
    if (tid < slice) MK[tid] = mb[tid];

    // ---- Q fragments: lane holds Q[w*16+l15][kd*32 + lhi*8 + 0..8)
    f16x8 qf[8];
    {
        const float* qrow = q_ + ((size_t)b * NLQ + w * 16 + l15) * NDK + lhi * 8;
        #pragma unroll
        for (int kd = 0; kd < 8; ++kd) {
            f32x4 x = *(const f32x4*)(qrow + kd * 32);
            f32x4 y = *(const f32x4*)(qrow + kd * 32 + 4);
            f16x8 f;
            f[0]=(f16)x[0]; f[1]=(f16)x[1]; f[2]=(f16)x[2]; f[3]=(f16)x[3];
            f[4]=(f16)y[0]; f[5]=(f16)y[1]; f[6]=(f16)y[2]; f[7]=(f16)y[3];
            qf[kd] = f;
        }
    }

    f32x4 accu[16];
    #pragma unroll
    for (int i = 0; i < 16; ++i) accu[i] = (f32x4){0.f, 0.f, 0.f, 0.f};
    float m_run = NEG, l_run = 0.f;

    f32x4 ks[4];   // staged K f32 for next tile

    // thread's staging coords: kk = r*8 + w, d = lane*4 (K tile 32x256 f32)
    auto stage = [&](f16* KAb) {
        #pragma unroll
        for (int r = 0; r < 4; ++r) {
            const int kk = r * 8 + w;
            const int d  = lane * 4;
            const int e  = kk * NDK + (d ^ ((kk & 15) << 3));
            f32x4 x = ks[r];
            f16x4 hh; hh[0]=(f16)x[0]; hh[1]=(f16)x[1]; hh[2]=(f16)x[2]; hh[3]=(f16)x[3];
            *(f16x4*)(KAb + e) = hh;
        }
    };

    // prologue: load + stage K tile 0
    #pragma unroll
    for (int r = 0; r < 4; ++r)
        ks[r] = *(const f32x4*)(kb + (r * 512 + tid) * 4);
    stage(KA[0]);
    __syncthreads();

    const int swz = l15 << 3;   // K read swizzle: row&15 == l15 for both halves

    for (int t = 0; t < nt; ++t) {
        const int cur = t & 1;
        if (t + 1 < nt) {   // prefetch next K tile (in flight through compute)
            const float* ksrc = kb + (size_t)(t + 1) * KT * NDK;
            #pragma unroll
            for (int r = 0; r < 4; ++r)
                ks[r] = *(const f32x4*)(ksrc + (r * 512 + tid) * 4);
        }
        const int k0 = t * KT;

        // ---- QK^T, both 16-key halves (A = K rows, B = Q)
        f32x4 s4a = (f32x4){0.f,0.f,0.f,0.f}, s4b = s4a;
        {
            const f16* k0p = &KA[cur][(0 * 16 + l15) * NDK];
            const f16* k1p = &KA[cur][(1 * 16 + l15) * NDK];
            #pragma unroll
            for (int kd = 0; kd < 8; ++kd) {
                const int col = (kd * 32 + lhi * 8) ^ swz;
                f16x8 kfa = *(const f16x8*)(k0p + col);
                s4a = __builtin_amdgcn_mfma_f32_16x16x32_f16(kfa, qf[kd], s4a, 0, 0, 0);
                f16x8 kfb = *(const f16x8*)(k1p + col);
                s4b = __builtin_amdgcn_mfma_f32_16x16x32_f16(kfb, qf[kd], s4b, 0, 0, 0);
            }
        }
        // s4a[j] = S[key=k0+lhi*4+j][q=l15], s4b[j] = S[key=k0+16+lhi*4+j][q=l15]

        // ---- mask -> -inf (from LDS), online softmax over 32 keys
        const int4 m4a = *(const int4*)(MK + k0 + lhi * 4);
        const int4 m4b = *(const int4*)(MK + k0 + 16 + lhi * 4);
        float sa[4], sb[4];
        sa[0] = m4a.x ? NEG : s4a[0]; sa[1] = m4a.y ? NEG : s4a[1];
        sa[2] = m4a.z ? NEG : s4a[2]; sa[3] = m4a.w ? NEG : s4a[3];
        sb[0] = m4b.x ? NEG : s4b[0]; sb[1] = m4b.y ? NEG : s4b[1];
        sb[2] = m4b.z ? NEG : s4b[2]; sb[3] = m4b.w ? NEG : s4b[3];

        float tmax = fmaxf(fmaxf(fmaxf(sa[0], sa[1]), fmaxf(sa[2], sa[3])),
                           fmaxf(fmaxf(sb[0], sb[1]), fmaxf(sb[2], sb[3])));
        tmax = fmaxf(tmax, __shfl_xor(tmax, 16, 64));
        tmax = fmaxf(tmax, __shfl_xor(tmax, 32, 64));
        const float mnew = fmaxf(m_run, tmax);
        const bool  dead = (mnew == NEG);
        const float scale = dead ? 1.f : __expf(m_run - mnew);
        float pa4[4], pb4[4];
        #pragma unroll
        for (int j = 0; j < 4; ++j) {
            pa4[j] = dead ? 0.f : __expf(sa[j] - mnew);
            pb4[j] = dead ? 0.f : __expf(sb[j] - mnew);
        }
        float ps = (pa4[0] + pa4[1]) + (pa4[2] + pa4[3])
                 + (pb4[0] + pb4[1]) + (pb4[2] + pb4[3]);
        ps += __shfl_xor(ps, 16, 64);
        ps += __shfl_xor(ps, 32, 64);
        l_run = l_run * scale + ps;
        m_run = mnew;

        f16x4 pa, pb;
        pa[0]=(f16)pa4[0]; pa[1]=(f16)pa4[1]; pa[2]=(f16)pa4[2]; pa[3]=(f16)pa4[3];
        pb[0]=(f16)pb4[0]; pb[1]=(f16)pb4[1]; pb[2]=(f16)pb4[2]; pb[3]=(f16)pb4[3];

        if (!__all(scale == 1.f)) {
            float scj[4];
            #pragma unroll
            for (int j = 0; j < 4; ++j) scj[j] = __shfl(scale, lhi * 4 + j, 64);
            #pragma unroll
            for (int d = 0; d < 16; ++d) {
                accu[d][0] *= scj[0]; accu[d][1] *= scj[1];
                accu[d][2] *= scj[2]; accu[d][3] *= scj[3];
            }
        }

        // ---- PV: B frag = V[row=h*16+lhi*4+j][dv=d*16+l15], f32 DIRECT from
        // global (r0-verified). 4-d groups: 16 independent loads, cvt, 4 MFMA.
        {
            const float* vr = vb + (size_t)(k0 + lhi * 4) * NDV + l15;
            #pragma unroll
            for (int h = 0; h < 2; ++h) {
                const f16x4 pfrag = h ? pb : pa;
                const float* vh = vr + (size_t)h * 16 * NDV;
                #pragma unroll
                for (int dg = 0; dg < 4; ++dg) {
                    float tv[4][4];
                    #pragma unroll
                    for (int dd = 0; dd < 4; ++dd) {
                        const float* vc = vh + (dg * 4 + dd) * 16;
                        tv[dd][0] = vc[0];
                        tv[dd][1] = vc[1 * NDV];
                        tv[dd][2] = vc[2 * NDV];
                        tv[dd][3] = vc[3 * NDV];
                    }
                    #pragma unroll
                    for (int dd = 0; dd < 4; ++dd) {
                        f16x4 vf;
                        vf[0]=(f16)tv[dd][0]; vf[1]=(f16)tv[dd][1];
                        vf[2]=(f16)tv[dd][2]; vf[3]=(f16)tv[dd][3];
                        accu[dg * 4 + dd] = __builtin_amdgcn_mfma_f32_16x16x16f16(
                            pfrag, vf, accu[dg * 4 + dd], 0, 0, 0);
                    }
                }
            }
        }

        if (t + 1 < nt) stage(KA[cur ^ 1]);
        __syncthreads();
    }

    // ---- write partials {acc (f16), m, l (f32)} to workspace
    const size_t base = (size_t)(b * S + s) * NLQ + w * 16;
    #pragma unroll
    for (int j = 0; j < 4; ++j) {
        f16* dst = accw + (base + lhi * 4 + j) * NDV + l15;
        #pragma unroll
        for (int d = 0; d < 16; ++d) dst[d * 16] = (f16)accu[d][j];
    }
    if (lane < 16) {
        mlw[(base + lane) * 2]     = m_run;
        mlw[(base + lane) * 2 + 1] = l_run;
    }
}

// ---------------- Kernel 2: merge key-splits, q-length mask, mean ----------
__global__ __launch_bounds__(256) void fvta_merge(
    const f16* __restrict__ accw, const float* __restrict__ mlw,
    const int* __restrict__ qlen_, float* __restrict__ out_, int S)
{
    __shared__ float fac[16][SPLITS + 1];
    const int qc = blockIdx.x, b = blockIdx.y, tid = threadIdx.x;
    const int len = qlen_[b];
    const float NEG = -__builtin_inff();

    if (tid < 16) {
        const int q = qc * 16 + tid;
        if (q < len) {
            float gm = NEG;
            for (int ss = 0; ss < S; ++ss)
                gm = fmaxf(gm, mlw[((size_t)(b * S + ss) * NLQ + q) * 2]);
            float L = 0.f;
            for (int ss = 0; ss < S; ++ss) {
                const float m = mlw[((size_t)(b * S + ss) * NLQ + q) * 2];
                const float l = mlw[((size_t)(b * S + ss) * NLQ + q) * 2 + 1];
                if (m != NEG) L += l * __expf(m - gm);
            }
            for (int ss = 0; ss < S; ++ss) {
                const float m = mlw[((size_t)(b * S + ss) * NLQ + q) * 2];
                fac[tid][ss] = (gm != NEG && L > 0.f && m != NEG)
                             ? __expf(m - gm) / L : 0.f;
            }
        } else {
            for (int ss = 0; ss < S; ++ss) fac[tid][ss] = 0.f;
        }
    }
    __syncthreads();

    float sum = 0.f;
    for (int qq = 0; qq < 16; ++qq) {
        const int q = qc * 16 + qq;
        for (int ss = 0; ss < S; ++ss) {
            const float f = fac[qq][ss];
            if (f != 0.f)
                sum += (float)accw[((size_t)(b * S + ss) * NLQ + q) * NDV + tid] * f;
        }
    }
    atomicAdd(&out_[b * NDV + tid], sum * (1.f / NLQ));
}

extern "C" void kernel_launch(void* const* d_in, const int* in_sizes, int n_in,
                              void* d_out, int out_size, void* d_ws, size_t ws_size,
                              hipStream_t stream) {
    const float* q    = (const float*)d_in[0];
    const int*   qlen = (const int*)d_in[1];
    const float* k    = (const float*)d_in[2];
    const float* v    = (const float*)d_in[3];
    const int*   mask = (const int*)d_in[4];
    float* out = (float*)d_out;

    int S = SPLITS;   // key splits; shrink if workspace is small
    while (S > 1 && ((size_t)NB * S * NLQ * NDV * 2 + (size_t)NB * S * NLQ * 8) > ws_size)
        S >>= 1;
    f16*   accw = (f16*)d_ws;
    float* mlw  = (float*)((char*)d_ws + (size_t)NB * S * NLQ * NDV * 2);

    hipMemsetAsync(out, 0, (size_t)out_size * sizeof(float), stream);
    dim3 g1(S, NB);
    fvta_part1<<<g1, 512, 0, stream>>>(q, k, v, mask, accw, mlw);
    dim3 g2(NLQ / 16, NB);
    fvta_merge<<<g2, 256, 0, stream>>>(accw, mlw, qlen, out, S);
}